// Round 19
// baseline (228.726 us; speedup 1.0000x reference)
//
#include <hip/hip_runtime.h>
#include <hip/hip_bf16.h>
#include <cstddef>
#include <cstdint>

#define BATCH 16
#define NPTS  4096
#define MPTS  1024
#define PTOT  65536
#define C1    128
#define C2    256

typedef short bf16x8 __attribute__((ext_vector_type(8)));
typedef float f32x4  __attribute__((ext_vector_type(4)));
typedef unsigned int u32x4 __attribute__((ext_vector_type(4)));

static __device__ __forceinline__ float bf2f(unsigned int u16) {
    union { unsigned int i; float f; } v; v.i = u16 << 16; return v.f;
}
static __device__ __forceinline__ unsigned short f2bf(float f) {
    union { float f; unsigned int i; } v; v.f = f;
    unsigned int u = v.i;
    return (unsigned short)((u + 0x7FFFu + ((u >> 16) & 1u)) >> 16);
}

static __device__ __forceinline__ void st_wt_b128(void* p, u32x4 v) {
    asm volatile("global_store_dwordx4 %0, %1, off sc0 sc1" :: "v"(p), "v"(v) : "memory");
}
static __device__ __forceinline__ void st_wt_f128(void* p, f32x4 v) {
    asm volatile("global_store_dwordx4 %0, %1, off sc0 sc1" :: "v"(p), "v"(v) : "memory");
}
static __device__ __forceinline__ void st_wt_b32(void* p, unsigned v) {
    asm volatile("global_store_dword %0, %1, off sc0 sc1" :: "v"(p), "v"(v) : "memory");
}
static __device__ __forceinline__ void st_wt_b16(void* p, unsigned v) {
    asm volatile("global_store_short %0, %1, off sc0 sc1" :: "v"(p), "v"(v) : "memory");
}

// ---------------------------------------------------------------------------
// Transpose (B, C, N) f32 -> (B, N, C) bf16 (kfT only)
// ---------------------------------------------------------------------------
template <int SWZ>
__global__ void k_transpose(const float* __restrict__ in, unsigned short* __restrict__ out,
                            int C, int N) {
    __shared__ float tile[64][65];
    int b  = blockIdx.z;
    int n0 = blockIdx.x * 64;
    int c0 = blockIdx.y * 64;
    const float* src = in + (size_t)b * C * N;
    unsigned short* dst = out + (size_t)b * N * C;
    int t  = threadIdx.x;
    int t4 = t >> 6;
    int tn = t & 63;
#pragma unroll
    for (int i = 0; i < 16; ++i) {
        int cc = i * 4 + t4;
        tile[cc][tn] = src[(size_t)(c0 + cc) * N + n0 + tn];
    }
    __syncthreads();
#pragma unroll
    for (int i = 0; i < 16; ++i) {
        int nn = i * 4 + t4;
        int p  = n0 + nn;
        int c  = c0 + tn;
        size_t off;
        if (SWZ) off = (size_t)p * C + (size_t)((((c >> 3) ^ (p & 7)) << 3) + (c & 7));
        else     off = (size_t)p * C + c;
        st_wt_b16(dst + off, (unsigned)f2bf(tile[tn][nn]));
    }
}

// ---------------------------------------------------------------------------
// Fused weight pack: one launch covers Wu (128 blk), W1 (256 blk), W2 (256).
// ---------------------------------------------------------------------------
__global__ void k_cvt_pack_all(const float* __restrict__ Wu, const float* __restrict__ W1,
                               const float* __restrict__ W2,
                               unsigned short* __restrict__ Wub,
                               unsigned short* __restrict__ W1b,
                               unsigned short* __restrict__ W2b) {
    int blk = blockIdx.x;
    const float* in; unsigned short* out; int K, lb;
    if (blk < 128)      { in = Wu; out = Wub; K = 128; lb = blk; }
    else if (blk < 384) { in = W1; out = W1b; K = 256; lb = blk - 128; }
    else                { in = W2; out = W2b; K = 256; lb = blk - 384; }
    int tid = lb * 256 + threadIdx.x;
    int ch = tid / K, k = tid % K;
    int ks = k >> 5, lhi = (k >> 3) & 3, e = k & 7;
    int wv = ch >> 6, i = (ch >> 4) & 3, llo = ch & 15;
    int lane = lhi * 16 + llo;
    st_wt_b16(out + ((size_t)((ks * 16 + wv * 4 + i) * 64 + lane)) * 8 + e,
              (unsigned)f2bf(in[tid]));
}

// ---------------------------------------------------------------------------
// three_nn: r16 4-thread/point version (known 46us). 64 pts/block, grid 1024.
// ---------------------------------------------------------------------------
static __device__ __forceinline__ bool nn_less(float da, int ia, float db, int ib) {
    return (da < db) || (da == db && ia < ib);
}

__global__ void k_three_nn(const float* __restrict__ unknown, const float* __restrict__ known,
                           int* __restrict__ idx_out, float* __restrict__ w_out) {
    __shared__ float4 kpt[MPTS + 4];
    int t  = threadIdx.x;
    int p0 = blockIdx.x * 64;
    int b  = p0 >> 12;
    const float* kb = known + (size_t)b * MPTS * 3;
    for (int i = t; i < MPTS; i += 256) {
        float x = kb[i * 3 + 0], y = kb[i * 3 + 1], z = kb[i * 3 + 2];
        float dd = __fadd_rn(__fadd_rn(__fmul_rn(x, x), __fmul_rn(y, y)), __fmul_rn(z, z));
        float4 v; v.x = x; v.y = y; v.z = z; v.w = dd;
        kpt[i + (i >> 8)] = v;
    }
    __syncthreads();

    int q = t & 3;
    int p = p0 + (t >> 2);
    const float* up = unknown + (size_t)p * 3;
    float ux = up[0], uy = up[1], uz = up[2];
    float u2 = __fadd_rn(__fadd_rn(__fmul_rn(ux, ux), __fmul_rn(uy, uy)), __fmul_rn(uz, uz));

    float d0 = INFINITY, d1 = INFINITY, d2 = INFINITY;
    int   i0 = 0, i1 = 0, i2 = 0;
    int base = q * 257;
#pragma unroll 4
    for (int it = 0; it < 256; ++it) {
        float4 kp = kpt[base + it];
        float dot = __fadd_rn(__fadd_rn(__fmul_rn(ux, kp.x), __fmul_rn(uy, kp.y)),
                              __fmul_rn(uz, kp.z));
        float d = __fsub_rn(__fadd_rn(u2, kp.w), __fmul_rn(2.0f, dot));
        int k = q * 256 + it;
        if (d < d0)      { d2 = d1; i2 = i1; d1 = d0; i1 = i0; d0 = d; i0 = k; }
        else if (d < d1) { d2 = d1; i2 = i1; d1 = d;  i1 = k; }
        else if (d < d2) { d2 = d;  i2 = k; }
    }

#pragma unroll
    for (int m = 1; m <= 2; m <<= 1) {
        float e0 = __shfl_xor(d0, m, 64), e1 = __shfl_xor(d1, m, 64), e2 = __shfl_xor(d2, m, 64);
        int   j0 = __shfl_xor(i0, m, 64), j1 = __shfl_xor(i1, m, 64), j2 = __shfl_xor(i2, m, 64);
        float a0 = d0, a1 = d1, a2 = d2; int x0 = i0, x1 = i1, x2 = i2;
        float b0 = e0, b1 = e1, b2 = e2; int y0 = j0, y1 = j1, y2 = j2;
        bool tk = nn_less(a0, x0, b0, y0);
        d0 = tk ? a0 : b0; i0 = tk ? x0 : y0;
        float na0 = tk ? a1 : a0; int nx0 = tk ? x1 : x0;
        float na1 = tk ? a2 : a1; int nx1 = tk ? x2 : x1;
        float nb0 = tk ? b0 : b1; int ny0 = tk ? y0 : y1;
        float nb1 = tk ? b1 : b2; int ny1 = tk ? y1 : y2;
        tk = nn_less(na0, nx0, nb0, ny0);
        d1 = tk ? na0 : nb0; i1 = tk ? nx0 : ny0;
        float ma0 = tk ? na1 : na0; int mx0 = tk ? nx1 : nx0;
        float mb0 = tk ? nb0 : nb1; int my0 = tk ? ny0 : ny1;
        tk = nn_less(ma0, mx0, mb0, my0);
        d2 = tk ? ma0 : mb0; i2 = tk ? mx0 : my0;
    }

    if (q == 0) {
        float r0 = 1.0f / (d0 + 1e-8f), r1 = 1.0f / (d1 + 1e-8f), r2 = 1.0f / (d2 + 1e-8f);
        float norm = r0 + r1 + r2;
        size_t pg = (size_t)p;
        st_wt_b32(idx_out + pg * 3 + 0, (unsigned)i0);
        st_wt_b32(idx_out + pg * 3 + 1, (unsigned)i1);
        st_wt_b32(idx_out + pg * 3 + 2, (unsigned)i2);
        union { float f; unsigned u; } w0v, w1v, w2v;
        w0v.f = r0 / norm; w1v.f = r1 / norm; w2v.f = r2 / norm;
        st_wt_b32(w_out + pg * 3 + 0, w0v.u);
        st_wt_b32(w_out + pg * 3 + 1, w1v.u);
        st_wt_b32(w_out + pg * 3 + 2, w2v.u);
    }
}

// ---------------------------------------------------------------------------
// GEMM, 16-pt tiles, grid 4096 (r18 shape, unchanged).
// MODE 1: manual staging + BN/relu apply (GEMM3).
// MODE 2 (K=128): stage from f32 (B,C1,N) d_in (GEMM1).
// MODE 3 (K=256): FUSED interpolate + BN0-skip staging (GEMM2).
// ---------------------------------------------------------------------------
template <int K, int MODE>
__global__ __launch_bounds__(256, 4) void k_gemm(
        const unsigned short* __restrict__ Wp,
        const unsigned short* __restrict__ X,
        const float* __restrict__ Xf,
        const unsigned short* __restrict__ kfT,
        const int* __restrict__ idx,
        const float* __restrict__ wgt,
        const float* __restrict__ bias,
        const float* __restrict__ aff_a,
        const float* __restrict__ aff_c,
        unsigned short* __restrict__ Y,
        float* __restrict__ partial) {
    constexpr int NK = K / 32;
    __shared__ char smem[8192];

    const int t    = threadIdx.x;
    const int p0   = blockIdx.x * 16;
    const int wv   = t >> 6;
    const int lane = t & 63;
    const int lhi  = lane >> 4, llo = lane & 15;

    if (MODE == 1) {
        constexpr int CPR = K / 8;
#pragma unroll
        for (int i = 0; i < (16 * CPR) / 256; ++i) {
            int f   = i * 256 + t;
            int row = f / CPR, qp = f % CPR;
            int col = qp ^ (row & 7);
            uint4 v = *(const uint4*)(X + (size_t)(p0 + row) * K + qp * 8);
            unsigned int w[4] = {v.x, v.y, v.z, v.w};
            float4 a0 = *(const float4*)(aff_a + col * 8);
            float4 a1 = *(const float4*)(aff_a + col * 8 + 4);
            float4 cc0 = *(const float4*)(aff_c + col * 8);
            float4 cc1 = *(const float4*)(aff_c + col * 8 + 4);
            float aa[8] = {a0.x, a0.y, a0.z, a0.w, a1.x, a1.y, a1.z, a1.w};
            float cc[8] = {cc0.x, cc0.y, cc0.z, cc0.w, cc1.x, cc1.y, cc1.z, cc1.w};
#pragma unroll
            for (int q2 = 0; q2 < 4; ++q2) {
                float lo = fmaxf(bf2f(w[q2] & 0xffff) * aa[q2 * 2]     + cc[q2 * 2],     0.0f);
                float hi = fmaxf(bf2f(w[q2] >> 16)    * aa[q2 * 2 + 1] + cc[q2 * 2 + 1], 0.0f);
                w[q2] = (unsigned int)f2bf(lo) | ((unsigned int)f2bf(hi) << 16);
            }
            uint4 o; o.x = w[0]; o.y = w[1]; o.z = w[2]; o.w = w[3];
            *(uint4*)(smem + row * (K * 2) + qp * 16) = o;
        }
    } else if (MODE == 2) {
        int c    = t >> 1;
        int half = (t & 1) * 8;
        int b    = p0 >> 12;
        const float* src = Xf + ((size_t)b * C1 + c) * NPTS + (p0 & 4095) + half;
        float4 v0 = *(const float4*)(src);
        float4 v1 = *(const float4*)(src + 4);
        float fv[8] = {v0.x, v0.y, v0.z, v0.w, v1.x, v1.y, v1.z, v1.w};
#pragma unroll
        for (int e = 0; e < 8; ++e) {
            int p = half + e;
            *(unsigned short*)(smem + p * (K * 2) +
                               ((((c >> 3) ^ (p & 7)) << 4) + (c & 7) * 2)) = f2bf(fv[e]);
        }
    } else {
        int pj  = t >> 4;
        int sub = t & 15;
        int p   = p0 + pj;
        int b   = p >> 12;
        int i0 = idx[p * 3 + 0], i1 = idx[p * 3 + 1], i2 = idx[p * 3 + 2];
        float w0 = wgt[p * 3 + 0], w1 = wgt[p * 3 + 1], w2 = wgt[p * 3 + 2];
        const unsigned short* kb = kfT + (size_t)b * MPTS * C2;
#pragma unroll
        for (int cc2 = 0; cc2 < 2; ++cc2) {
            int cc = sub * 2 + cc2;
            int cbase = cc * 8;
            u32x4 v0 = *(const u32x4*)(kb + (size_t)i0 * C2 + cbase);
            u32x4 v1 = *(const u32x4*)(kb + (size_t)i1 * C2 + cbase);
            u32x4 v2 = *(const u32x4*)(kb + (size_t)i2 * C2 + cbase);
            int pos = cc ^ (p & 7);
            u32x4 vy = *(const u32x4*)(X + (size_t)p * C2 + pos * 8);
            float4 a0 = *(const float4*)(aff_a + cbase);
            float4 a1 = *(const float4*)(aff_a + cbase + 4);
            float4 c0f = *(const float4*)(aff_c + cbase);
            float4 c1f = *(const float4*)(aff_c + cbase + 4);
            float aa[8] = {a0.x, a0.y, a0.z, a0.w, a1.x, a1.y, a1.z, a1.w};
            float cf[8] = {c0f.x, c0f.y, c0f.z, c0f.w, c1f.x, c1f.y, c1f.z, c1f.w};
            unsigned r[4];
#pragma unroll
            for (int qq = 0; qq < 4; ++qq) {
                float lo = w0 * bf2f(v0[qq] & 0xffff) + w1 * bf2f(v1[qq] & 0xffff)
                         + w2 * bf2f(v2[qq] & 0xffff)
                         + bf2f(vy[qq] & 0xffff) * aa[qq * 2] + cf[qq * 2];
                float hi = w0 * bf2f(v0[qq] >> 16) + w1 * bf2f(v1[qq] >> 16)
                         + w2 * bf2f(v2[qq] >> 16)
                         + bf2f(vy[qq] >> 16) * aa[qq * 2 + 1] + cf[qq * 2 + 1];
                r[qq] = (unsigned)f2bf(lo) | ((unsigned)f2bf(hi) << 16);
            }
            u32x4 vo; vo.x = r[0]; vo.y = r[1]; vo.z = r[2]; vo.w = r[3];
            *(u32x4*)(smem + pj * 512 + pos * 16) = vo;
        }
    }

    const unsigned short* wbase = Wp + ((size_t)(wv * 256) + lane) * 8;
    bf16x8 wA[4], wB[4];
#pragma unroll
    for (int i = 0; i < 4; ++i)
        wA[i] = *(const bf16x8*)(wbase + i * 512);

    __syncthreads();

    f32x4 acc[4];
#pragma unroll
    for (int i = 0; i < 4; ++i) acc[i] = (f32x4){0.f, 0.f, 0.f, 0.f};

#pragma unroll
    for (int ks = 0; ks < NK; ks += 2) {
#pragma unroll
        for (int i = 0; i < 4; ++i)
            wB[i] = *(const bf16x8*)(wbase + (size_t)(ks + 1) * 8192 + i * 512);
        {
            int cp = (ks * 4 + lhi) ^ (llo & 7);
            bf16x8 bb = *(const bf16x8*)(smem + llo * (K * 2) + cp * 16);
#pragma unroll
            for (int i = 0; i < 4; ++i)
                acc[i] = __builtin_amdgcn_mfma_f32_16x16x32_bf16(wA[i], bb, acc[i], 0, 0, 0);
        }
        if (ks + 2 < NK) {
#pragma unroll
            for (int i = 0; i < 4; ++i)
                wA[i] = *(const bf16x8*)(wbase + (size_t)(ks + 2) * 8192 + i * 512);
        }
        {
            int cp = ((ks + 1) * 4 + lhi) ^ (llo & 7);
            bf16x8 bb = *(const bf16x8*)(smem + llo * (K * 2) + cp * 16);
#pragma unroll
            for (int i = 0; i < 4; ++i)
                acc[i] = __builtin_amdgcn_mfma_f32_16x16x32_bf16(wB[i], bb, acc[i], 0, 0, 0);
        }
    }

    __syncthreads();
#pragma unroll
    for (int i = 0; i < 4; ++i) {
        int cbase = wv * 64 + i * 16 + lhi * 4;
        float4 bv = *(const float4*)(bias + cbase);
        int c8 = cbase >> 3, hf = lhi & 1;
        int row = llo;
        float y0 = acc[i][0] + bv.x;
        float y1 = acc[i][1] + bv.y;
        float y2 = acc[i][2] + bv.z;
        float y3 = acc[i][3] + bv.w;
        float s0 = y0, q0 = y0 * y0;
        float s1 = y1, q1 = y1 * y1;
        float s2 = y2, q2 = y2 * y2;
        float s3 = y3, q3 = y3 * y3;
        unsigned int lo = (unsigned int)f2bf(y0) | ((unsigned int)f2bf(y1) << 16);
        unsigned int hi = (unsigned int)f2bf(y2) | ((unsigned int)f2bf(y3) << 16);
        uint2 o; o.x = lo; o.y = hi;
        *(uint2*)(smem + row * 512 + ((c8 ^ (row & 7)) << 4) + hf * 8) = o;
#pragma unroll
        for (int m = 1; m <= 8; m <<= 1) {
            s0 += __shfl_xor(s0, m, 64); q0 += __shfl_xor(q0, m, 64);
            s1 += __shfl_xor(s1, m, 64); q1 += __shfl_xor(q1, m, 64);
            s2 += __shfl_xor(s2, m, 64); q2 += __shfl_xor(q2, m, 64);
            s3 += __shfl_xor(s3, m, 64); q3 += __shfl_xor(q3, m, 64);
        }
        if (llo == 0) {
            f32x4 sv = {s0, s1, s2, s3};
            f32x4 qv = {q0, q1, q2, q3};
            st_wt_f128(partial + (size_t)blockIdx.x * 512 + cbase, sv);
            st_wt_f128(partial + (size_t)blockIdx.x * 512 + 256 + cbase, qv);
        }
    }
    __syncthreads();
    {
        const char* ysrc = smem + t * 16;
        char* ydst = (char*)(Y + (size_t)p0 * 256) + t * 16;
        u32x4 v0 = *(const u32x4*)(ysrc);
        u32x4 v1 = *(const u32x4*)(ysrc + 4096);
        st_wt_b128(ydst, v0);
        st_wt_b128(ydst + 4096, v1);
    }
}

// ---------------------------------------------------------------------------
// Fused stats: 64 blocks reduce 4096 partials -> partA; last-arriving block
// finalizes affine (fixed-order sums -> bit-deterministic output).
// ---------------------------------------------------------------------------
__global__ void k_stats(const float* __restrict__ partial, float* __restrict__ partA,
                        const float* __restrict__ gamma, const float* __restrict__ beta,
                        float* __restrict__ aff_a, float* __restrict__ aff_c,
                        unsigned* __restrict__ counter) {
    int t = threadIdx.x, g = blockIdx.x;
    float s = 0.f, q = 0.f;
#pragma unroll 8
    for (int i = 0; i < 64; ++i) {
        const float* pp = partial + (size_t)(g * 64 + i) * 512;
        s += pp[t]; q += pp[256 + t];
    }
    partA[g * 512 + t]       = s;
    partA[g * 512 + 256 + t] = q;
    __threadfence();
    __syncthreads();
    __shared__ unsigned lastv;
    if (t == 0) lastv = atomicAdd(counter, 1u);
    __syncthreads();
    if (lastv == 63u) {
        __threadfence();
        float s2 = 0.f, q2 = 0.f;
#pragma unroll 8
        for (int i = 0; i < 64; ++i) {
            s2 += partA[i * 512 + t];
            q2 += partA[i * 512 + 256 + t];
        }
        float mean = s2 * (1.0f / PTOT);
        float var  = fmaxf(q2 * (1.0f / PTOT) - mean * mean, 0.0f);
        float a    = gamma[t] / sqrtf(var + 1e-5f);
        aff_a[t] = a;
        aff_c[t] = beta[t] - mean * a;
    }
}

// ---------------------------------------------------------------------------
// Final: out(B,256,n) f32 = relu(y2*a2+c2), from swizzled (P,256) bf16.
// ---------------------------------------------------------------------------
__global__ void k_final(const unsigned short* __restrict__ Y2, const float* __restrict__ aff_a,
                        const float* __restrict__ aff_c, float* __restrict__ out) {
    __shared__ float tile[64][65];
    int p0 = blockIdx.x * 64;
    int c0 = blockIdx.y * 64;
    int t  = threadIdx.x;
    int t4 = t >> 6, t64 = t & 63;
#pragma unroll
    for (int i = 0; i < 16; ++i) {
        int r = i * 4 + t4;
        int p = p0 + r;
        int c = c0 + t64;
        float v = bf2f(Y2[(size_t)p * 256 + (((c >> 3) ^ (p & 7)) << 3) + (c & 7)])
                  * aff_a[c] + aff_c[c];
        tile[t64][r] = fmaxf(v, 0.0f);
    }
    __syncthreads();
    int b   = p0 >> 12;
    int pin = p0 & 4095;
#pragma unroll
    for (int i = 0; i < 16; ++i) {
        int cc = i * 4 + t4;
        __builtin_nontemporal_store(tile[cc][t64],
            out + ((size_t)b * 256 + c0 + cc) * 4096 + pin + t64);
    }
}

// ---------------------------------------------------------------------------
extern "C" void kernel_launch(void* const* d_in, const int* in_sizes, int n_in,
                              void* d_out, int out_size, void* d_ws, size_t ws_size,
                              hipStream_t stream) {
    const float* unknown = (const float*)d_in[0];
    const float* known   = (const float*)d_in[1];
    const float* ufeat   = (const float*)d_in[2];
    const float* kfeat   = (const float*)d_in[3];
    const float* Wu      = (const float*)d_in[4];
    const float* bu      = (const float*)d_in[5];
    const float* gu      = (const float*)d_in[6];
    const float* betau   = (const float*)d_in[7];
    const float* W1      = (const float*)d_in[8];
    const float* b1      = (const float*)d_in[9];
    const float* g1      = (const float*)d_in[10];
    const float* beta1   = (const float*)d_in[11];
    const float* W2      = (const float*)d_in[12];
    const float* b2      = (const float*)d_in[13];
    const float* g2      = (const float*)d_in[14];
    const float* beta2   = (const float*)d_in[15];
    float* out = (float*)d_out;

    char* ws = (char*)d_ws;
    unsigned short* reg0 = (unsigned short*)ws;                        // 32MB: part0 -> y1
    unsigned short* ybuf = (unsigned short*)(ws + ((size_t)32 << 20)); // 32MB: y0 -> y2
    unsigned short* kfT  = (unsigned short*)(ws + ((size_t)64 << 20)); // 8MB (alive thru GEMM2)
    unsigned short* Wub  = (unsigned short*)(ws + ((size_t)72 << 20)); // 64KB (packed)
    unsigned short* W1b  = Wub + 256 * 128;                            // 128KB (packed)
    unsigned short* W2b  = W1b + 256 * 256;                            // 128KB (packed)
    int*   idxb = (int*)(W2b + 256 * 256);                             // 768KB
    float* wgtb = (float*)(idxb + (size_t)PTOT * 3);                   // 768KB
    float* affa0 = wgtb + (size_t)PTOT * 3;
    float* affc0 = affa0 + 256;
    float* affa1 = affc0 + 256;
    float* affc1 = affa1 + 256;
    float* affa2 = affc1 + 256;
    float* affc2 = affa2 + 256;
    float* partA = affc2 + 256;                                        // 128KB shared reduce buf
    unsigned* cnts = (unsigned*)(partA + 64 * 512);                    // 12B (3 counters)
    float* part0  = (float*)ws;                                        // 8MB (reg0 region, pre-y1)
    float* partD  = (float*)d_out;                                     // GEMM2/3 partials: d_out
                                                                       // scratch (overwritten by
                                                                       // k_final afterwards)
    if (ws_size < ((size_t)75 << 20)) return;

    // stats counters must start at 0 each call (ws poisoned once before timing)
    hipMemsetAsync(cnts, 0, 12, stream);

    // 1) layout prep
    k_transpose<0><<<dim3(MPTS / 64, C2 / 64, BATCH), 256, 0, stream>>>(kfeat, kfT, C2, MPTS);
    k_cvt_pack_all<<<640, 256, 0, stream>>>(Wu, W1, W2, Wub, W1b, W2b);

    // 2) three_nn (4 threads/point, r16 version)
    k_three_nn<<<PTOT / 64, 256, 0, stream>>>(unknown, known, idxb, wgtb);

    // 3) y0 = Wu @ ufeat + bu  (MODE 2)
    k_gemm<C1, 2><<<PTOT / 16, 256, 0, stream>>>(Wub, nullptr, ufeat, nullptr, nullptr, nullptr,
                                                 bu, nullptr, nullptr, ybuf, part0);
    k_stats<<<64, 256, 0, stream>>>(part0, partA, gu, betau, affa0, affc0, cnts + 0);

    // 4) y1 = W1 @ (interp + BN0(y0)) + b1  (MODE 3 fused)
    k_gemm<C2, 3><<<PTOT / 16, 256, 0, stream>>>(W1b, ybuf, nullptr, kfT, idxb, wgtb,
                                                 b1, affa0, affc0, reg0, partD);
    k_stats<<<64, 256, 0, stream>>>(partD, partA, g1, beta1, affa1, affc1, cnts + 1);

    // 5) y2 = W2 @ relu(BN1(y1)) + b2 (MODE 1)
    k_gemm<C2, 1><<<PTOT / 16, 256, 0, stream>>>(W2b, reg0, nullptr, nullptr, nullptr, nullptr,
                                                 b2, affa1, affc1, ybuf, partD);
    k_stats<<<64, 256, 0, stream>>>(partD, partA, g2, beta2, affa2, affc2, cnts + 2);

    // 6) out = relu(BN2(y2)) transposed to (B, 256, n) f32
    k_final<<<dim3(PTOT / 64, 4), 256, 0, stream>>>(ybuf, affa2, affc2, out);

    (void)in_sizes; (void)n_in; (void)out_size;
}

// Round 20
// 209.364 us; speedup vs baseline: 1.0925x; 1.0925x over previous
//
#include <hip/hip_runtime.h>
#include <hip/hip_bf16.h>
#include <cstddef>
#include <cstdint>

#define BATCH 16
#define NPTS  4096
#define MPTS  1024
#define PTOT  65536
#define C1    128
#define C2    256

typedef short bf16x8 __attribute__((ext_vector_type(8)));
typedef float f32x4  __attribute__((ext_vector_type(4)));
typedef unsigned int u32x4 __attribute__((ext_vector_type(4)));

static __device__ __forceinline__ float bf2f(unsigned int u16) {
    union { unsigned int i; float f; } v; v.i = u16 << 16; return v.f;
}
static __device__ __forceinline__ unsigned short f2bf(float f) {
    union { float f; unsigned int i; } v; v.f = f;
    unsigned int u = v.i;
    return (unsigned short)((u + 0x7FFFu + ((u >> 16) & 1u)) >> 16);
}

static __device__ __forceinline__ void st_wt_b128(void* p, u32x4 v) {
    asm volatile("global_store_dwordx4 %0, %1, off sc0 sc1" :: "v"(p), "v"(v) : "memory");
}
static __device__ __forceinline__ void st_wt_f128(void* p, f32x4 v) {
    asm volatile("global_store_dwordx4 %0, %1, off sc0 sc1" :: "v"(p), "v"(v) : "memory");
}
static __device__ __forceinline__ void st_wt_b32(void* p, unsigned v) {
    asm volatile("global_store_dword %0, %1, off sc0 sc1" :: "v"(p), "v"(v) : "memory");
}
static __device__ __forceinline__ void st_wt_b16(void* p, unsigned v) {
    asm volatile("global_store_short %0, %1, off sc0 sc1" :: "v"(p), "v"(v) : "memory");
}

// ---------------------------------------------------------------------------
// Transpose (B, C, N) f32 -> (B, N, C) bf16 (kfT only)
// ---------------------------------------------------------------------------
template <int SWZ>
__global__ void k_transpose(const float* __restrict__ in, unsigned short* __restrict__ out,
                            int C, int N) {
    __shared__ float tile[64][65];
    int b  = blockIdx.z;
    int n0 = blockIdx.x * 64;
    int c0 = blockIdx.y * 64;
    const float* src = in + (size_t)b * C * N;
    unsigned short* dst = out + (size_t)b * N * C;
    int t  = threadIdx.x;
    int t4 = t >> 6;
    int tn = t & 63;
#pragma unroll
    for (int i = 0; i < 16; ++i) {
        int cc = i * 4 + t4;
        tile[cc][tn] = src[(size_t)(c0 + cc) * N + n0 + tn];
    }
    __syncthreads();
#pragma unroll
    for (int i = 0; i < 16; ++i) {
        int nn = i * 4 + t4;
        int p  = n0 + nn;
        int c  = c0 + tn;
        size_t off;
        if (SWZ) off = (size_t)p * C + (size_t)((((c >> 3) ^ (p & 7)) << 3) + (c & 7));
        else     off = (size_t)p * C + c;
        st_wt_b16(dst + off, (unsigned)f2bf(tile[tn][nn]));
    }
}

// ---------------------------------------------------------------------------
// Weight pack: (256, K) f32 -> bf16 fragment-packed [K/32][16][64 lane][8].
// ---------------------------------------------------------------------------
__global__ void k_cvt_pack(const float* __restrict__ in, unsigned short* __restrict__ out, int K) {
    int tid = blockIdx.x * 256 + threadIdx.x;
    if (tid >= 256 * K) return;
    int ch = tid / K, k = tid % K;
    int ks = k >> 5, lhi = (k >> 3) & 3, e = k & 7;
    int wv = ch >> 6, i = (ch >> 4) & 3, llo = ch & 15;
    int lane = lhi * 16 + llo;
    st_wt_b16(out + ((size_t)((ks * 16 + wv * 4 + i) * 64 + lane)) * 8 + e,
              (unsigned)f2bf(in[tid]));
}

// ---------------------------------------------------------------------------
// three_nn, branchless packed-key version. key = (flip(bits(d)) << 10) | k:
// unsigned 64-bit ordering == (d, idx) lexicographic (exact top_k semantics).
// d computed with the identical rounded expression as the reference.
// 4 threads/point, 64 pts/block, grid 1024 (r16/r17 geometry).
// ---------------------------------------------------------------------------
static __device__ __forceinline__ void key_insert3(unsigned long long key,
                                                   unsigned long long& k0,
                                                   unsigned long long& k1,
                                                   unsigned long long& k2) {
    bool c0 = key < k0, c1 = key < k1, c2 = key < k2;
    unsigned long long n2 = c1 ? k1 : (c2 ? key : k2);
    unsigned long long n1 = c0 ? k0 : (c1 ? key : k1);
    unsigned long long n0 = c0 ? key : k0;
    k0 = n0; k1 = n1; k2 = n2;
}

__global__ void k_three_nn(const float* __restrict__ unknown, const float* __restrict__ known,
                           int* __restrict__ idx_out, float* __restrict__ w_out) {
    __shared__ float4 kpt[MPTS + 4];
    int t  = threadIdx.x;
    int p0 = blockIdx.x * 64;
    int b  = p0 >> 12;
    const float* kb = known + (size_t)b * MPTS * 3;
    for (int i = t; i < MPTS; i += 256) {
        float x = kb[i * 3 + 0], y = kb[i * 3 + 1], z = kb[i * 3 + 2];
        float dd = __fadd_rn(__fadd_rn(__fmul_rn(x, x), __fmul_rn(y, y)), __fmul_rn(z, z));
        float4 v; v.x = x; v.y = y; v.z = z; v.w = dd;
        kpt[i + (i >> 8)] = v;
    }
    __syncthreads();

    int q = t & 3;
    int p = p0 + (t >> 2);
    const float* up = unknown + (size_t)p * 3;
    float ux = up[0], uy = up[1], uz = up[2];
    float u2 = __fadd_rn(__fadd_rn(__fmul_rn(ux, ux), __fmul_rn(uy, uy)), __fmul_rn(uz, uz));

    unsigned long long k0 = ~0ULL, k1 = ~0ULL, k2 = ~0ULL;
    int base = q * 257;
#pragma unroll 4
    for (int it = 0; it < 256; ++it) {
        float4 kp = kpt[base + it];
        float dot = __fadd_rn(__fadd_rn(__fmul_rn(ux, kp.x), __fmul_rn(uy, kp.y)),
                              __fmul_rn(uz, kp.z));
        float d = __fsub_rn(__fadd_rn(u2, kp.w), __fmul_rn(2.0f, dot));
        union { float f; unsigned u; } db; db.f = d;
        unsigned key32 = db.u ^ (unsigned)(((int)db.u >> 31) | 0x80000000);
        unsigned long long key = ((unsigned long long)key32 << 10) | (unsigned)(q * 256 + it);
        key_insert3(key, k0, k1, k2);
    }

    // merge across the 4 chunk-lanes (keys carry exact (d, idx) order)
#pragma unroll
    for (int m = 1; m <= 2; m <<= 1) {
        unsigned long long e0 = __shfl_xor(k0, m, 64);
        unsigned long long e1 = __shfl_xor(k1, m, 64);
        unsigned long long e2 = __shfl_xor(k2, m, 64);
        key_insert3(e0, k0, k1, k2);
        key_insert3(e1, k0, k1, k2);
        key_insert3(e2, k0, k1, k2);
    }

    if (q == 0) {
        unsigned long long kk[3] = {k0, k1, k2};
        float dd[3]; int ii[3];
#pragma unroll
        for (int j = 0; j < 3; ++j) {
            ii[j] = (int)(kk[j] & 1023ULL);
            unsigned key32 = (unsigned)(kk[j] >> 10);
            unsigned bits = (key32 & 0x80000000u) ? (key32 ^ 0x80000000u) : ~key32;
            union { unsigned u; float f; } fb; fb.u = bits;
            dd[j] = fb.f;
        }
        float r0 = 1.0f / (dd[0] + 1e-8f), r1 = 1.0f / (dd[1] + 1e-8f), r2 = 1.0f / (dd[2] + 1e-8f);
        float norm = r0 + r1 + r2;
        size_t pg = (size_t)p;
        st_wt_b32(idx_out + pg * 3 + 0, (unsigned)ii[0]);
        st_wt_b32(idx_out + pg * 3 + 1, (unsigned)ii[1]);
        st_wt_b32(idx_out + pg * 3 + 2, (unsigned)ii[2]);
        union { float f; unsigned u; } w0v, w1v, w2v;
        w0v.f = r0 / norm; w1v.f = r1 / norm; w2v.f = r2 / norm;
        st_wt_b32(w_out + pg * 3 + 0, w0v.u);
        st_wt_b32(w_out + pg * 3 + 1, w1v.u);
        st_wt_b32(w_out + pg * 3 + 2, w2v.u);
    }
}

// ---------------------------------------------------------------------------
// GEMM, 32-pt tiles, grid 2048, 34KB LDS (r17-proven config, unchanged).
// MODE 1: manual staging + BN/relu apply (GEMM3).
// MODE 2 (K=128): stage from f32 (B,C1,N) d_in (GEMM1).
// MODE 3 (K=256): FUSED interpolate + BN0-skip staging (GEMM2).
// ---------------------------------------------------------------------------
template <int K, int MODE>
__global__ __launch_bounds__(256, 4) void k_gemm(
        const unsigned short* __restrict__ Wp,
        const unsigned short* __restrict__ X,
        const float* __restrict__ Xf,
        const unsigned short* __restrict__ kfT,
        const int* __restrict__ idx,
        const float* __restrict__ wgt,
        const float* __restrict__ bias,
        const float* __restrict__ aff_a,
        const float* __restrict__ aff_c,
        unsigned short* __restrict__ Y,
        float* __restrict__ partial) {
    constexpr int NK = K / 32;
    __shared__ char smem[34816];

    const int t    = threadIdx.x;
    const int p0   = blockIdx.x * 32;
    const int wv   = t >> 6;
    const int lane = t & 63;
    const int lhi  = lane >> 4, llo = lane & 15;

    if (MODE == 1) {
        constexpr int CPR = K / 8;
#pragma unroll
        for (int i = 0; i < (32 * CPR) / 256; ++i) {
            int f   = i * 256 + t;
            int row = f / CPR, qp = f % CPR;
            int col = qp ^ (row & 7);
            uint4 v = *(const uint4*)(X + (size_t)(p0 + row) * K + qp * 8);
            unsigned int w[4] = {v.x, v.y, v.z, v.w};
            float4 a0 = *(const float4*)(aff_a + col * 8);
            float4 a1 = *(const float4*)(aff_a + col * 8 + 4);
            float4 cc0 = *(const float4*)(aff_c + col * 8);
            float4 cc1 = *(const float4*)(aff_c + col * 8 + 4);
            float aa[8] = {a0.x, a0.y, a0.z, a0.w, a1.x, a1.y, a1.z, a1.w};
            float cc[8] = {cc0.x, cc0.y, cc0.z, cc0.w, cc1.x, cc1.y, cc1.z, cc1.w};
#pragma unroll
            for (int q2 = 0; q2 < 4; ++q2) {
                float lo = fmaxf(bf2f(w[q2] & 0xffff) * aa[q2 * 2]     + cc[q2 * 2],     0.0f);
                float hi = fmaxf(bf2f(w[q2] >> 16)    * aa[q2 * 2 + 1] + cc[q2 * 2 + 1], 0.0f);
                w[q2] = (unsigned int)f2bf(lo) | ((unsigned int)f2bf(hi) << 16);
            }
            uint4 o; o.x = w[0]; o.y = w[1]; o.z = w[2]; o.w = w[3];
            *(uint4*)(smem + row * (K * 2) + qp * 16) = o;
        }
    } else if (MODE == 2) {
        int c    = t >> 1;
        int half = (t & 1) * 16;
        int b    = p0 >> 12;
        const float* src = Xf + ((size_t)b * C1 + c) * NPTS + (p0 & 4095) + half;
#pragma unroll
        for (int k4 = 0; k4 < 4; ++k4) {
            float4 v = *(const float4*)(src + k4 * 4);
            float fv[4] = {v.x, v.y, v.z, v.w};
#pragma unroll
            for (int e = 0; e < 4; ++e) {
                int p = half + k4 * 4 + e;
                *(unsigned short*)(smem + p * (K * 2) +
                                   ((((c >> 3) ^ (p & 7)) << 4) + (c & 7) * 2)) = f2bf(fv[e]);
            }
        }
    } else {
        int pj  = t >> 3;
        int sub = t & 7;
        int p   = p0 + pj;
        int b   = p >> 12;
        int i0 = idx[p * 3 + 0], i1 = idx[p * 3 + 1], i2 = idx[p * 3 + 2];
        float w0 = wgt[p * 3 + 0], w1 = wgt[p * 3 + 1], w2 = wgt[p * 3 + 2];
        const unsigned short* kb = kfT + (size_t)b * MPTS * C2;
#pragma unroll
        for (int cc2 = 0; cc2 < 4; ++cc2) {
            int cc = sub * 4 + cc2;
            int cbase = cc * 8;
            u32x4 v0 = *(const u32x4*)(kb + (size_t)i0 * C2 + cbase);
            u32x4 v1 = *(const u32x4*)(kb + (size_t)i1 * C2 + cbase);
            u32x4 v2 = *(const u32x4*)(kb + (size_t)i2 * C2 + cbase);
            int pos = cc ^ (p & 7);
            u32x4 vy = *(const u32x4*)(X + (size_t)p * C2 + pos * 8);
            float4 a0 = *(const float4*)(aff_a + cbase);
            float4 a1 = *(const float4*)(aff_a + cbase + 4);
            float4 c0f = *(const float4*)(aff_c + cbase);
            float4 c1f = *(const float4*)(aff_c + cbase + 4);
            float aa[8] = {a0.x, a0.y, a0.z, a0.w, a1.x, a1.y, a1.z, a1.w};
            float cf[8] = {c0f.x, c0f.y, c0f.z, c0f.w, c1f.x, c1f.y, c1f.z, c1f.w};
            unsigned r[4];
#pragma unroll
            for (int qq = 0; qq < 4; ++qq) {
                float lo = w0 * bf2f(v0[qq] & 0xffff) + w1 * bf2f(v1[qq] & 0xffff)
                         + w2 * bf2f(v2[qq] & 0xffff)
                         + bf2f(vy[qq] & 0xffff) * aa[qq * 2] + cf[qq * 2];
                float hi = w0 * bf2f(v0[qq] >> 16) + w1 * bf2f(v1[qq] >> 16)
                         + w2 * bf2f(v2[qq] >> 16)
                         + bf2f(vy[qq] >> 16) * aa[qq * 2 + 1] + cf[qq * 2 + 1];
                r[qq] = (unsigned)f2bf(lo) | ((unsigned)f2bf(hi) << 16);
            }
            u32x4 vo; vo.x = r[0]; vo.y = r[1]; vo.z = r[2]; vo.w = r[3];
            *(u32x4*)(smem + pj * 512 + pos * 16) = vo;
        }
    }

    const unsigned short* wbase = Wp + ((size_t)(wv * 256) + lane) * 8;
    bf16x8 wA[4], wB[4];
#pragma unroll
    for (int i = 0; i < 4; ++i)
        wA[i] = *(const bf16x8*)(wbase + i * 512);

    __syncthreads();

    f32x4 acc[4][2];
#pragma unroll
    for (int i = 0; i < 4; ++i)
#pragma unroll
        for (int j = 0; j < 2; ++j) acc[i][j] = (f32x4){0.f, 0.f, 0.f, 0.f};

#pragma unroll
    for (int ks = 0; ks < NK; ks += 2) {
#pragma unroll
        for (int i = 0; i < 4; ++i)
            wB[i] = *(const bf16x8*)(wbase + (size_t)(ks + 1) * 8192 + i * 512);
        {
            bf16x8 bb[2];
#pragma unroll
            for (int j = 0; j < 2; ++j) {
                int row = j * 16 + llo;
                int cp  = (ks * 4 + lhi) ^ (row & 7);
                bb[j] = *(const bf16x8*)(smem + row * (K * 2) + cp * 16);
            }
#pragma unroll
            for (int i = 0; i < 4; ++i)
#pragma unroll
                for (int j = 0; j < 2; ++j)
                    acc[i][j] = __builtin_amdgcn_mfma_f32_16x16x32_bf16(wA[i], bb[j], acc[i][j], 0, 0, 0);
        }
        if (ks + 2 < NK) {
#pragma unroll
            for (int i = 0; i < 4; ++i)
                wA[i] = *(const bf16x8*)(wbase + (size_t)(ks + 2) * 8192 + i * 512);
        }
        {
            bf16x8 bb[2];
#pragma unroll
            for (int j = 0; j < 2; ++j) {
                int row = j * 16 + llo;
                int cp  = ((ks + 1) * 4 + lhi) ^ (row & 7);
                bb[j] = *(const bf16x8*)(smem + row * (K * 2) + cp * 16);
            }
#pragma unroll
            for (int i = 0; i < 4; ++i)
#pragma unroll
                for (int j = 0; j < 2; ++j)
                    acc[i][j] = __builtin_amdgcn_mfma_f32_16x16x32_bf16(wB[i], bb[j], acc[i][j], 0, 0, 0);
        }
    }

    __syncthreads();
#pragma unroll
    for (int i = 0; i < 4; ++i) {
        int cbase = wv * 64 + i * 16 + lhi * 4;
        float4 bv = *(const float4*)(bias + cbase);
        int c8 = cbase >> 3, hf = lhi & 1;
        float s0 = 0.f, s1 = 0.f, s2 = 0.f, s3 = 0.f;
        float q0 = 0.f, q1 = 0.f, q2 = 0.f, q3 = 0.f;
#pragma unroll
        for (int j = 0; j < 2; ++j) {
            int row = j * 16 + llo;
            float y0 = acc[i][j][0] + bv.x;
            float y1 = acc[i][j][1] + bv.y;
            float y2 = acc[i][j][2] + bv.z;
            float y3 = acc[i][j][3] + bv.w;
            s0 += y0; q0 += y0 * y0;  s1 += y1; q1 += y1 * y1;
            s2 += y2; q2 += y2 * y2;  s3 += y3; q3 += y3 * y3;
            unsigned int lo = (unsigned int)f2bf(y0) | ((unsigned int)f2bf(y1) << 16);
            unsigned int hi = (unsigned int)f2bf(y2) | ((unsigned int)f2bf(y3) << 16);
            uint2 o; o.x = lo; o.y = hi;
            *(uint2*)(smem + row * 512 + ((c8 ^ (row & 7)) << 4) + hf * 8) = o;
        }
#pragma unroll
        for (int m = 1; m <= 8; m <<= 1) {
            s0 += __shfl_xor(s0, m, 64); q0 += __shfl_xor(q0, m, 64);
            s1 += __shfl_xor(s1, m, 64); q1 += __shfl_xor(q1, m, 64);
            s2 += __shfl_xor(s2, m, 64); q2 += __shfl_xor(q2, m, 64);
            s3 += __shfl_xor(s3, m, 64); q3 += __shfl_xor(q3, m, 64);
        }
        if (llo == 0) {
            f32x4 sv = {s0, s1, s2, s3};
            f32x4 qv = {q0, q1, q2, q3};
            st_wt_f128(partial + (size_t)blockIdx.x * 512 + cbase, sv);
            st_wt_f128(partial + (size_t)blockIdx.x * 512 + 256 + cbase, qv);
        }
    }
    __syncthreads();
    {
        const char* ysrc = smem + t * 16;
        char* ydst = (char*)(Y + (size_t)p0 * 256) + t * 16;
#pragma unroll
        for (int i2 = 0; i2 < 4; ++i2) {
            u32x4 v = *(const u32x4*)(ysrc + i2 * 4096);
            st_wt_b128(ydst + i2 * 4096, v);
        }
    }
}

// ---------------------------------------------------------------------------
// Stats reduce: 2048 block-partials -> 64 -> affine(a,c)
// ---------------------------------------------------------------------------
__global__ void k_red1(const float* __restrict__ partial, float* __restrict__ partA) {
    int t = threadIdx.x, g = blockIdx.x;
    float s = 0.f, q = 0.f;
#pragma unroll 8
    for (int i = 0; i < 32; ++i) {
        const float* pp = partial + (size_t)(g * 32 + i) * 512;
        s += pp[t]; q += pp[256 + t];
    }
    union { float f; unsigned u; } sv, qv; sv.f = s; qv.f = q;
    st_wt_b32(partA + g * 512 + t, sv.u);
    st_wt_b32(partA + g * 512 + 256 + t, qv.u);
}

__global__ void k_finalize(const float* __restrict__ partA, const float* __restrict__ gamma,
                           const float* __restrict__ beta, float* __restrict__ aff_a,
                           float* __restrict__ aff_c) {
    int c = threadIdx.x;
    float s = 0.f, q = 0.f;
#pragma unroll 8
    for (int i = 0; i < 64; ++i) { s += partA[i * 512 + c]; q += partA[i * 512 + 256 + c]; }
    float mean = s * (1.0f / PTOT);
    float var  = fmaxf(q * (1.0f / PTOT) - mean * mean, 0.0f);
    float a    = gamma[c] / sqrtf(var + 1e-5f);
    union { float f; unsigned u; } av, cv;
    av.f = a; cv.f = beta[c] - mean * a;
    st_wt_b32(aff_a + c, av.u);
    st_wt_b32(aff_c + c, cv.u);
}

// ---------------------------------------------------------------------------
// Final: out(B,256,n) f32 = relu(y2*a2+c2), from swizzled (P,256) bf16.
// ---------------------------------------------------------------------------
__global__ void k_final(const unsigned short* __restrict__ Y2, const float* __restrict__ aff_a,
                        const float* __restrict__ aff_c, float* __restrict__ out) {
    __shared__ float tile[64][65];
    int p0 = blockIdx.x * 64;
    int c0 = blockIdx.y * 64;
    int t  = threadIdx.x;
    int t4 = t >> 6, t64 = t & 63;
#pragma unroll
    for (int i = 0; i < 16; ++i) {
        int r = i * 4 + t4;
        int p = p0 + r;
        int c = c0 + t64;
        float v = bf2f(Y2[(size_t)p * 256 + (((c >> 3) ^ (p & 7)) << 3) + (c & 7)])
                  * aff_a[c] + aff_c[c];
        tile[t64][r] = fmaxf(v, 0.0f);
    }
    __syncthreads();
    int b   = p0 >> 12;
    int pin = p0 & 4095;
#pragma unroll
    for (int i = 0; i < 16; ++i) {
        int cc = i * 4 + t4;
        __builtin_nontemporal_store(tile[cc][t64],
            out + ((size_t)b * 256 + c0 + cc) * 4096 + pin + t64);
    }
}

// ---------------------------------------------------------------------------
extern "C" void kernel_launch(void* const* d_in, const int* in_sizes, int n_in,
                              void* d_out, int out_size, void* d_ws, size_t ws_size,
                              hipStream_t stream) {
    const float* unknown = (const float*)d_in[0];
    const float* known   = (const float*)d_in[1];
    const float* ufeat   = (const float*)d_in[2];
    const float* kfeat   = (const float*)d_in[3];
    const float* Wu      = (const float*)d_in[4];
    const float* bu      = (const float*)d_in[5];
    const float* gu      = (const float*)d_in[6];
    const float* betau   = (const float*)d_in[7];
    const float* W1      = (const float*)d_in[8];
    const float* b1      = (const float*)d_in[9];
    const float* g1      = (const float*)d_in[10];
    const float* beta1   = (const float*)d_in[11];
    const float* W2      = (const float*)d_in[12];
    const float* b2      = (const float*)d_in[13];
    const float* g2      = (const float*)d_in[14];
    const float* beta2   = (const float*)d_in[15];
    float* out = (float*)d_out;

    char* ws = (char*)d_ws;
    unsigned short* reg0 = (unsigned short*)ws;                        // 32MB: part0 -> y1
    unsigned short* ybuf = (unsigned short*)(ws + ((size_t)32 << 20)); // 32MB: y0 -> y2
    unsigned short* kfT  = (unsigned short*)(ws + ((size_t)64 << 20)); // 8MB (alive thru GEMM2)
    unsigned short* Wub  = (unsigned short*)(ws + ((size_t)72 << 20)); // 64KB (packed)
    unsigned short* W1b  = Wub + 256 * 128;                            // 128KB (packed)
    unsigned short* W2b  = W1b + 256 * 256;                            // 128KB (packed)
    int*   idxb = (int*)(W2b + 256 * 256);                             // 768KB
    float* wgtb = (float*)(idxb + (size_t)PTOT * 3);                   // 768KB
    float* affa0 = wgtb + (size_t)PTOT * 3;
    float* affc0 = affa0 + 256;
    float* affa1 = affc0 + 256;
    float* affc1 = affa1 + 256;
    float* affa2 = affc1 + 256;
    float* affc2 = affa2 + 256;
    float* partA = affc2 + 256;                                        // 128KB shared reduce buf
    float* part0  = (float*)ws;                                        // 4MB (reg0 region, pre-y1)
    float* partD  = (float*)d_out;                                     // GEMM2/3 partials: d_out
                                                                       // scratch (overwritten by
                                                                       // k_final afterwards)
    if (ws_size < ((size_t)75 << 20)) return;

    // 1) layout prep
    k_transpose<0><<<dim3(MPTS / 64, C2 / 64, BATCH), 256, 0, stream>>>(kfeat, kfT, C2, MPTS);
    k_cvt_pack<<<128, 256, 0, stream>>>(Wu, Wub, 128);
    k_cvt_pack<<<256, 256, 0, stream>>>(W1, W1b, 256);
    k_cvt_pack<<<256, 256, 0, stream>>>(W2, W2b, 256);

    // 2) three_nn (branchless packed-key)
    k_three_nn<<<PTOT / 64, 256, 0, stream>>>(unknown, known, idxb, wgtb);

    // 3) y0 = Wu @ ufeat + bu  (MODE 2, 32-pt, 2048 blocks)
    k_gemm<C1, 2><<<PTOT / 32, 256, 0, stream>>>(Wub, nullptr, ufeat, nullptr, nullptr, nullptr,
                                                 bu, nullptr, nullptr, ybuf, part0);
    k_red1<<<64, 256, 0, stream>>>(part0, partA);
    k_finalize<<<1, 256, 0, stream>>>(partA, gu, betau, affa0, affc0);

    // 4) y1 = W1 @ (interp + BN0(y0)) + b1  (MODE 3 fused)
    k_gemm<C2, 3><<<PTOT / 32, 256, 0, stream>>>(W1b, ybuf, nullptr, kfT, idxb, wgtb,
                                                 b1, affa0, affc0, reg0, partD);
    k_red1<<<64, 256, 0, stream>>>(partD, partA);
    k_finalize<<<1, 256, 0, stream>>>(partA, g1, beta1, affa1, affc1);

    // 5) y2 = W2 @ relu(BN1(y1)) + b2 (MODE 1)
    k_gemm<C2, 1><<<PTOT / 32, 256, 0, stream>>>(W2b, reg0, nullptr, nullptr, nullptr, nullptr,
                                                 b2, affa1, affc1, ybuf, partD);
    k_red1<<<64, 256, 0, stream>>>(partD, partA);
    k_finalize<<<1, 256, 0, stream>>>(partA, g2, beta2, affa2, affc2);

    // 6) out = relu(BN2(y2)) transposed to (B, 256, n) f32
    k_final<<<dim3(PTOT / 64, 4), 256, 0, stream>>>(ybuf, affa2, affc2, out);

    (void)in_sizes; (void)n_in; (void)out_size;
}